// Round 6
// baseline (132018.970 us; speedup 1.0000x reference)
//
#include <hip/hip_runtime.h>
#include <math.h>

#define TT    100000
#define HH    74
#define G4    296          // 4*H gate rows per layer
#define KH    40           // per-thread K half (74 padded to 80)
#define SLOT  80           // h-ring / LDS h slot stride (floats, 16B aligned)
#define ZSLOT 304          // zx-ring / LDS zx slot stride (296 pad to 304)
#define NT    704          // 640 row threads (320 rows x 2 halves) + helper wave
#define W5    640

typedef float f4 __attribute__((ext_vector_type(4)));

#define ALD(p)    __hip_atomic_load((p),  __ATOMIC_RELAXED, __HIP_MEMORY_SCOPE_AGENT)
#define ALDA(p)   __hip_atomic_load((p),  __ATOMIC_ACQUIRE, __HIP_MEMORY_SCOPE_AGENT)
#define AST(p,v)  __hip_atomic_store((p),(v),__ATOMIC_RELAXED, __HIP_MEMORY_SCOPE_AGENT)
#define ASTR(p,v) __hip_atomic_store((p),(v),__ATOMIC_RELEASE, __HIP_MEMORY_SCOPE_AGENT)

__global__ void init_ctrl(unsigned* ctrl) {
    ctrl[threadIdx.x] = 0u;   // 256 dwords; ws is poisoned 0xAA each launch
}

// 6 pipeline stages: bid 2l = A_l (zx = W_ih*inp + b), bid 2l+1 = B_l (recurrence).
// 40 weight floats/thread -> register-resident even at a 68-VGPR allocation.
__launch_bounds__(NT, 1)
__global__ void lstm_pipe6(const float* __restrict__ seasons,
                           const float* __restrict__ W_ih,
                           const float* __restrict__ W_hh,
                           const float* __restrict__ b_ih,
                           const float* __restrict__ b_hh,
                           const float* __restrict__ W_lin,
                           const float* __restrict__ b_lin,
                           float* __restrict__ out,
                           unsigned* ctrl,
                           float* zbase, float* hbase, int CZ, int CH)
{
    const int  bid = blockIdx.x;      // 0..5
    const int  l   = bid >> 1;        // layer
    const bool isA = (bid & 1) == 0;
    const int  tid = threadIdx.x;

    __shared__ __align__(16) float sIn[2][SLOT];   // A: layer input (dbuf)
    __shared__ __align__(16) float sZ[2][ZSLOT];   // A: zx out-stage | B: zx in-stage
    __shared__ __align__(16) float sH[SLOT];       // B: h(t-1)
    __shared__ float sG[G4];                       // B: activated gates

    unsigned* cnt_out = ctrl + bid * 32;
    unsigned* cnt_in  = ctrl + (bid > 0 ? (bid - 1) * 32 : 0);
    unsigned* cnt_dn  = ctrl + (bid < 5 ? (bid + 1) * 32 : 0);

    float* zring     = zbase + (size_t)l * CZ * ZSLOT;              // A_l -> B_l
    float* hring_out = hbase + (size_t)l * CH * SLOT;               // B_l -> A_{l+1}
    float* hring_in  = (l > 0) ? hbase + (size_t)(l-1) * CH * SLOT : (float*)0;

    // ---- LDS init: h(-1)=0 (incl pad), zero sIn pads ----
    if (tid < SLOT) sH[tid] = 0.0f;
    if (tid >= SLOT && tid < SLOT + 2*(SLOT-HH)) {
        int k = tid - SLOT;
        sIn[k/(SLOT-HH)][HH + k%(SLOT-HH)] = 0.0f;
    }

    // ---- weights: lane pair per row, one K-half each (40 floats) ----
    const bool isRowT = (tid < W5);
    const int  row  = (tid >> 6) * 32 + ((tid & 63) >> 1);   // 0..319 (>=296 pad)
    const int  half = tid & 1;
    const int  wrow = (row < G4) ? row : (G4 - 1);

    f4 w0={0,0,0,0},w1={0,0,0,0},w2={0,0,0,0},w3={0,0,0,0},w4={0,0,0,0},
       w5={0,0,0,0},w6={0,0,0,0},w7={0,0,0,0},w8={0,0,0,0},w9={0,0,0,0};
    float bias = 0.0f;

    if (isRowT) {
        const bool  isG = (wrow >= 2*HH) && (wrow < 3*HH);   // fold tanh's 2x
        const float sc  = isG ? 2.0f : 1.0f;
        const float* src = (isA ? W_ih : W_hh) + (size_t)(l*G4 + wrow) * HH;
#define LDW(V, Q) { \
        int k0 = half*KH + 4*(Q); \
        int ka=k0, kb=k0+1, kc=k0+2, kd=k0+3; \
        float va=src[ka<HH?ka:0], vb=src[kb<HH?kb:0]; \
        float vc=src[kc<HH?kc:0], vd=src[kd<HH?kd:0]; \
        V[0] = ka<HH ? sc*va : 0.0f;  V[1] = kb<HH ? sc*vb : 0.0f; \
        V[2] = kc<HH ? sc*vc : 0.0f;  V[3] = kd<HH ? sc*vd : 0.0f; }
        LDW(w0,0) LDW(w1,1) LDW(w2,2) LDW(w3,3) LDW(w4,4)
        LDW(w5,5) LDW(w6,6) LDW(w7,7) LDW(w8,8) LDW(w9,9)
#undef LDW
        // pin: opaque def -> backend cannot sink/remat the loads into the loop
        asm volatile("" : "+v"(w0),"+v"(w1),"+v"(w2),"+v"(w3),"+v"(w4),
                          "+v"(w5),"+v"(w6),"+v"(w7),"+v"(w8),"+v"(w9));
        if (isA && half == 0)
            bias = sc * (b_ih[l*G4 + wrow] + b_hh[l*G4 + wrow]);
    }

    float wl0 = 0.f, wl1 = 0.f, blin = 0.f;
    if (bid == 5 && tid >= W5) {                 // final linear on B2 helper
        int lane = tid - W5;
        wl0 = W_lin[lane];
        wl1 = (lane < HH-64) ? W_lin[64 + lane] : 0.0f;
        blin = b_lin[0];
    }

    __syncthreads();

    // ---- prologue (helper wave): stage step-0 input + step-1 regs ----
    float ir0 = 0.f, ir1 = 0.f;                       // A input stream
    float zr0=0.f, zr1=0.f, zr2=0.f, zr3=0.f, zr4=0.f; // B zx stream
    unsigned cin = 0, cons = 0;
    if (tid >= W5) {
        const int lane = tid - W5;
        if (isA) {
            if (l == 0) {
                sIn[0][lane] = seasons[lane];
                if (lane < HH-64) sIn[0][64+lane] = seasons[64+lane];
                ir0 = seasons[HH + lane];
                if (lane < HH-64) ir1 = seasons[HH + 64 + lane];
            } else {
                do { cin = ALDA(cnt_in); } while (cin < 2u);
                sIn[0][lane] = ALD(hring_in + lane);
                if (lane < HH-64) sIn[0][64+lane] = ALD(hring_in + 64 + lane);
                const float* rs = hring_in + (size_t)(1 % CH) * SLOT;
                ir0 = ALD(rs + lane);
                if (lane < HH-64) ir1 = ALD(rs + 64 + lane);
            }
        } else {
            do { cin = ALDA(cnt_in); } while (cin < 2u);
            sZ[0][lane]       = ALD(zring + lane);
            sZ[0][64 + lane]  = ALD(zring + 64 + lane);
            sZ[0][128 + lane] = ALD(zring + 128 + lane);
            sZ[0][192 + lane] = ALD(zring + 192 + lane);
            if (lane < G4-256) sZ[0][256 + lane] = ALD(zring + 256 + lane);
            const float* rs = zring + (size_t)(1 % CZ) * ZSLOT;
            zr0 = ALD(rs + lane);        zr1 = ALD(rs + 64 + lane);
            zr2 = ALD(rs + 128 + lane);  zr3 = ALD(rs + 192 + lane);
            zr4 = (lane < G4-256) ? ALD(rs + 256 + lane) : 0.0f;
        }
    }
    __syncthreads();

    float c = 0.0f;            // cell state (B rows, tid < 74)
    float pf = 0.0f;           // L2 touch-prefetch sink (A0 helper)

    for (int t = 0; t < TT; ++t) {
        const int b = t & 1;
        if (isRowT) {
            float a0, a1 = 0.f, a2 = 0.f, a3 = 0.f;
            const f4* vv;
            if (isA) {
                vv = ((const f4*)sIn[b]) + half*(KH/4);
                a0 = bias;
            } else {
                vv = ((const f4*)sH) + half*(KH/4);
                a0 = (half == 0 && row < G4) ? sZ[b][row] : 0.0f;   // zx (has bias)
            }
            // even lanes read f4[0..9], odd f4[10..19]: 160B apart, disjoint banks
#define ACC4(W, Q) { f4 v_ = vv[Q]; \
            a0 = fmaf(W[0], v_[0], a0); a1 = fmaf(W[1], v_[1], a1); \
            a2 = fmaf(W[2], v_[2], a2); a3 = fmaf(W[3], v_[3], a3); }
            ACC4(w0,0) ACC4(w1,1) ACC4(w2,2) ACC4(w3,3) ACC4(w4,4)
            ACC4(w5,5) ACC4(w6,6) ACC4(w7,7) ACC4(w8,8) ACC4(w9,9)
#undef ACC4
            float p = (a0 + a1) + (a2 + a3);
            p += __shfl_xor(p, 1, 64);                   // combine K-halves
            if (isA) {
                if (half == 0 && row < G4) sZ[b][row] = p;
            } else {
                float s = __builtin_amdgcn_rcpf(1.0f + __expf(-p));
                const bool isG = (row >= 2*HH) && (row < 3*HH);
                float g = isG ? fmaf(2.0f, s, -1.0f) : s;  // tanh = 2*sigm(2x)-1
                if (half == 0 && row < G4) sG[row] = g;
            }
        } else {
            const int lane = tid - W5;
            if (isA) {
                if (t > 0) {   // drain zx(t-1) -> ring, publish
                    while ((long)(t-1) - (long)cons > (long)(CZ - 8))
                        cons = ALD(cnt_dn);
                    const int ob = (t-1) & 1;
                    float v0 = sZ[ob][lane],      v1 = sZ[ob][64+lane];
                    float v2 = sZ[ob][128+lane],  v3 = sZ[ob][192+lane];
                    float v4 = (lane < G4-256) ? sZ[ob][256+lane] : 0.0f;
                    float* rs = zring + (size_t)((t-1) % CZ) * ZSLOT;
                    AST(rs + lane, v0);        AST(rs + 64 + lane, v1);
                    AST(rs + 128 + lane, v2);  AST(rs + 192 + lane, v3);
                    if (lane < G4-256) AST(rs + 256 + lane, v4);
                    if (lane == 0) ASTR(cnt_out, (unsigned)t);  // orders this wave's stores
                }
                const int nb = (t + 1) & 1;                     // inp(t+1) from regs
                sIn[nb][lane] = ir0;
                if (lane < HH-64) sIn[nb][64+lane] = ir1;
                if (t + 2 < TT) {                               // issue inp(t+2)
                    if (l == 0) {
                        const float* xs = seasons + (size_t)(t+2) * HH;
                        ir0 = xs[lane];
                        if (lane < HH-64) ir1 = xs[64+lane];
                        if (t + 16 < TT) pf += seasons[(size_t)(t+16)*HH + lane];
                    } else {
                        if (cin < (unsigned)(t+3)) {
                            do { cin = ALDA(cnt_in); } while (cin < (unsigned)(t+3));
                        }
                        const float* rs2 = hring_in + (size_t)((t+2) % CH) * SLOT;
                        ir0 = ALD(rs2 + lane);
                        if (lane < HH-64) ir1 = ALD(rs2 + 64 + lane);
                        cin = ALD(cnt_in);
                    }
                }
            } else {
                if (t > 0) {
                    if (l < 2) {           // h(t-1) -> ring, publish
                        float h0 = sH[lane];
                        float h1 = (lane < HH-64) ? sH[64+lane] : 0.0f;
                        while ((long)(t-1) - (long)cons > (long)(CH - 8))
                            cons = ALD(cnt_dn);
                        float* rs = hring_out + (size_t)((t-1) % CH) * SLOT;
                        AST(rs + lane, h0);
                        if (lane < HH-64) AST(rs + 64 + lane, h1);
                        if (lane == 0) ASTR(cnt_out, (unsigned)t);
                    } else {               // final linear + relu
                        if (lane == 0) AST(cnt_out, (unsigned)t);   // progress for A2
                        float p = wl0 * sH[lane];
                        if (lane < HH-64) p += wl1 * sH[64 + lane];
                        #pragma unroll
                        for (int m = 32; m >= 1; m >>= 1)
                            p += __shfl_xor(p, m, 64);
                        if (lane == 0) out[t-1] = fmaxf(p + blin, 0.0f);
                    }
                }
                const int nb = (t + 1) & 1;                     // zx(t+1) from regs
                sZ[nb][lane] = zr0;        sZ[nb][64+lane] = zr1;
                sZ[nb][128+lane] = zr2;    sZ[nb][192+lane] = zr3;
                if (lane < G4-256) sZ[nb][256+lane] = zr4;
                if (t + 2 < TT) {                               // issue zx(t+2)
                    if (cin < (unsigned)(t+3)) {
                        do { cin = ALDA(cnt_in); } while (cin < (unsigned)(t+3));
                    }
                    const float* rs2 = zring + (size_t)((t+2) % CZ) * ZSLOT;
                    zr0 = ALD(rs2 + lane);       zr1 = ALD(rs2 + 64 + lane);
                    zr2 = ALD(rs2 + 128 + lane); zr3 = ALD(rs2 + 192 + lane);
                    if (lane < G4-256) zr4 = ALD(rs2 + 256 + lane);
                    cin = ALD(cnt_in);
                }
            }
        }
        __syncthreads();   // barrier1: A done / B gates ready + staging done

        if (!isA) {
            // ---- Phase B: cell update ----
            if (tid < HH) {
                float iv = sG[tid];
                float fv = sG[HH + tid];
                float gv = sG[2*HH + tid];
                float ov = sG[3*HH + tid];
                c = fmaf(fv, c, iv * gv);
                float e  = __expf(-2.0f * fabsf(c));             // overflow-safe tanh
                float th = copysignf((1.0f - e) * __builtin_amdgcn_rcpf(1.0f + e), c);
                sH[tid] = ov * th;
            }
            __syncthreads();   // barrier2: h(t) ready
        }
    }

    // ---- epilogue: flush final step ----
    if (tid >= W5) {
        const int lane = tid - W5;
        if (isA) {
            const int ob = (TT-1) & 1;
            float v0 = sZ[ob][lane],      v1 = sZ[ob][64+lane];
            float v2 = sZ[ob][128+lane],  v3 = sZ[ob][192+lane];
            float v4 = (lane < G4-256) ? sZ[ob][256+lane] : 0.0f;
            float* rs = zring + (size_t)((TT-1) % CZ) * ZSLOT;
            AST(rs + lane, v0);        AST(rs + 64 + lane, v1);
            AST(rs + 128 + lane, v2);  AST(rs + 192 + lane, v3);
            if (lane < G4-256) AST(rs + 256 + lane, v4);
            if (lane == 0) ASTR(cnt_out, (unsigned)TT);
        } else if (l < 2) {
            float h0 = sH[lane];
            float h1 = (lane < HH-64) ? sH[64+lane] : 0.0f;
            float* rs = hring_out + (size_t)((TT-1) % CH) * SLOT;
            AST(rs + lane, h0);
            if (lane < HH-64) AST(rs + 64 + lane, h1);
            if (lane == 0) ASTR(cnt_out, (unsigned)TT);
        } else {
            float p = wl0 * sH[lane];
            if (lane < HH-64) p += wl1 * sH[64 + lane];
            #pragma unroll
            for (int m = 32; m >= 1; m >>= 1)
                p += __shfl_xor(p, m, 64);
            if (lane == 0) out[TT-1] = fmaxf(p + blin, 0.0f);
        }
    }
    asm volatile("" :: "v"(pf));   // keep prefetch sum live
}

extern "C" void kernel_launch(void* const* d_in, const int* in_sizes, int n_in,
                              void* d_out, int out_size, void* d_ws, size_t ws_size,
                              hipStream_t stream)
{
    (void)in_sizes; (void)n_in; (void)out_size;
    const float* seasons = (const float*)d_in[0];
    const float* W_ih  = (const float*)d_in[1];
    const float* W_hh  = (const float*)d_in[2];
    const float* b_ih  = (const float*)d_in[3];
    const float* b_hh  = (const float*)d_in[4];
    const float* W_lin = (const float*)d_in[5];
    const float* b_lin = (const float*)d_in[6];
    float* out = (float*)d_out;

    unsigned* ctrl = (unsigned*)d_ws;
    float* zbase = (float*)((char*)d_ws + 4096);
    long avail = ((long)ws_size - 4096) / 4;       // floats available
    int CZ = 256, CH = 1024;                        // ~1.6 MB -> L2-resident
    while ((3L*CZ*ZSLOT + 2L*CH*SLOT) > avail && CZ > 16) { CZ >>= 1; CH >>= 1; }
    if (CZ < 16) CZ = 16;
    if (CH < 16) CH = 16;
    float* hbase = zbase + 3L * CZ * ZSLOT;

    hipLaunchKernelGGL(init_ctrl, dim3(1), dim3(256), 0, stream, ctrl);
    hipLaunchKernelGGL(lstm_pipe6, dim3(6), dim3(NT), 0, stream,
                       seasons, W_ih, W_hh, b_ih, b_hh, W_lin, b_lin,
                       out, ctrl, zbase, hbase, CZ, CH);
}

// Round 7
// 77223.206 us; speedup vs baseline: 1.7096x; 1.7096x over previous
//
#include <hip/hip_runtime.h>
#include <math.h>

#define TT    100000
#define HH    74
#define G4    296          // 4*H gate rows per layer
#define KH    40           // per-thread K half (74 padded to 80)
#define SLOT  80           // h-ring / LDS h slot stride (floats)
#define ZSLOT 304          // zx-ring / LDS zx slot stride (296 pad to 304)
#define NT    768          // 10 row waves + prefetch wave + publish wave
#define W5    640          // start of prefetch wave
#define W6    704          // start of publish wave

typedef float f4 __attribute__((ext_vector_type(4)));

#define ALD(p)    __hip_atomic_load((p),  __ATOMIC_RELAXED, __HIP_MEMORY_SCOPE_AGENT)
#define ALDA(p)   __hip_atomic_load((p),  __ATOMIC_ACQUIRE, __HIP_MEMORY_SCOPE_AGENT)
#define AST(p,v)  __hip_atomic_store((p),(v),__ATOMIC_RELAXED, __HIP_MEMORY_SCOPE_AGENT)
#define ASTR(p,v) __hip_atomic_store((p),(v),__ATOMIC_RELEASE, __HIP_MEMORY_SCOPE_AGENT)

// Barrier WITHOUT vmcnt drain: intra-block comm is LDS-only (lgkm), so row
// waves sync cheaply and the prefetch wave's HBM ring loads stay in flight
// across the barrier (the vmcnt(0) in __syncthreads was exposing ~900cy/step).
#define BAR() asm volatile("s_waitcnt lgkmcnt(0)\n\ts_barrier" ::: "memory")

__global__ void init_ctrl(unsigned* ctrl) {
    ctrl[threadIdx.x] = 0u;   // 256 dwords; ws is poisoned 0xAA each launch
}

__launch_bounds__(NT, 1)
__global__ void lstm_pipe6(const float* __restrict__ seasons,
                           const float* __restrict__ W_ih,
                           const float* __restrict__ W_hh,
                           const float* __restrict__ b_ih,
                           const float* __restrict__ b_hh,
                           const float* __restrict__ W_lin,
                           const float* __restrict__ b_lin,
                           float* __restrict__ out,
                           unsigned* ctrl,
                           float* zbase, float* hbase, int CZ, int CH)
{
    const int  bid = blockIdx.x;      // 0..5
    const int  l   = bid >> 1;        // layer
    const bool isA = (bid & 1) == 0;
    const int  tid = threadIdx.x;

    __shared__ __align__(16) float sIn[2][SLOT];   // A: layer input (dbuf)
    __shared__ __align__(16) float sZ[2][ZSLOT];   // A: zx out-dbuf | B: zx in-dbuf
    __shared__ __align__(16) float sH[SLOT];       // B: h(t-1)
    __shared__ float sG[G4];                       // B: activated gates

    unsigned* cnt_out = ctrl + bid * 32;
    unsigned* cnt_in  = ctrl + (bid > 0 ? (bid - 1) * 32 : 0);
    unsigned* cnt_dn  = ctrl + (bid < 5 ? (bid + 1) * 32 : 0);

    float* zring     = zbase + (size_t)l * CZ * ZSLOT;              // A_l -> B_l
    float* hring_out = hbase + (size_t)l * CH * SLOT;               // B_l -> A_{l+1}
    float* hring_in  = (l > 0) ? hbase + (size_t)(l-1) * CH * SLOT : (float*)0;

    // ---- LDS init: h(-1)=0 (incl pad), zero sIn pads ----
    if (tid < SLOT) sH[tid] = 0.0f;
    if (tid >= SLOT && tid < SLOT + 2*(SLOT-HH)) {
        int k = tid - SLOT;
        sIn[k/(SLOT-HH)][HH + k%(SLOT-HH)] = 0.0f;
    }

    // ---- weights: lane pair per row, one K-half each (40 floats, pinned) ----
    const bool isRowT = (tid < W5);
    const int  row  = (tid >> 6) * 32 + ((tid & 63) >> 1);   // 0..319 (>=296 pad)
    const int  half = tid & 1;
    const int  wrow = (row < G4) ? row : (G4 - 1);

    f4 w0={0,0,0,0},w1={0,0,0,0},w2={0,0,0,0},w3={0,0,0,0},w4={0,0,0,0},
       w5={0,0,0,0},w6={0,0,0,0},w7={0,0,0,0},w8={0,0,0,0},w9={0,0,0,0};
    float bias = 0.0f;

    if (isRowT) {
        const bool  isG = (wrow >= 2*HH) && (wrow < 3*HH);   // fold tanh's 2x
        const float sc  = isG ? 2.0f : 1.0f;
        const float* src = (isA ? W_ih : W_hh) + (size_t)(l*G4 + wrow) * HH;
#define LDW(V, Q) { \
        int k0 = half*KH + 4*(Q); \
        int ka=k0, kb=k0+1, kc=k0+2, kd=k0+3; \
        float va=src[ka<HH?ka:0], vb=src[kb<HH?kb:0]; \
        float vc=src[kc<HH?kc:0], vd=src[kd<HH?kd:0]; \
        V[0] = ka<HH ? sc*va : 0.0f;  V[1] = kb<HH ? sc*vb : 0.0f; \
        V[2] = kc<HH ? sc*vc : 0.0f;  V[3] = kd<HH ? sc*vd : 0.0f; }
        LDW(w0,0) LDW(w1,1) LDW(w2,2) LDW(w3,3) LDW(w4,4)
        LDW(w5,5) LDW(w6,6) LDW(w7,7) LDW(w8,8) LDW(w9,9)
#undef LDW
        // pin: opaque def -> backend cannot sink/remat the loads into the loop
        asm volatile("" : "+v"(w0),"+v"(w1),"+v"(w2),"+v"(w3),"+v"(w4),
                          "+v"(w5),"+v"(w6),"+v"(w7),"+v"(w8),"+v"(w9));
        if (isA && half == 0)
            bias = sc * (b_ih[l*G4 + wrow] + b_hh[l*G4 + wrow]);
    }

    float wl0 = 0.f, wl1 = 0.f, blin = 0.f;
    if (bid == 5 && tid >= W6) {                 // final linear on publish wave
        int lane = tid - W6;
        wl0 = W_lin[lane];
        wl1 = (lane < HH-64) ? W_lin[64 + lane] : 0.0f;
        blin = b_lin[0];
    }

    __syncthreads();

    // ---- prologue (prefetch wave): LDS buf0 = slot0; regset A = slot1, B = slot2 ----
    float irA0=0.f, irA1=0.f, irB0=0.f, irB1=0.f;                 // A input stream
    float zA0=0.f,zA1=0.f,zA2=0.f,zA3=0.f,zA4=0.f;                // B zx stream (even)
    float zB0=0.f,zB1=0.f,zB2=0.f,zB3=0.f,zB4=0.f;                // B zx stream (odd)
    unsigned cin = 0, cons = 0;
    if (tid >= W5 && tid < W6) {
        const int lane = tid - W5;
        if (isA) {
            if (l == 0) {
                sIn[0][lane] = seasons[lane];
                if (lane < HH-64) sIn[0][64+lane] = seasons[64+lane];
                irA0 = seasons[HH + lane];
                if (lane < HH-64) irA1 = seasons[HH + 64 + lane];
                irB0 = seasons[2*HH + lane];
                if (lane < HH-64) irB1 = seasons[2*HH + 64 + lane];
            } else {
                do { cin = ALDA(cnt_in); } while (cin < 3u);
                sIn[0][lane] = ALD(hring_in + lane);
                if (lane < HH-64) sIn[0][64+lane] = ALD(hring_in + 64 + lane);
                const float* r1 = hring_in + (size_t)(1 % CH) * SLOT;
                irA0 = ALD(r1 + lane);
                if (lane < HH-64) irA1 = ALD(r1 + 64 + lane);
                const float* r2 = hring_in + (size_t)(2 % CH) * SLOT;
                irB0 = ALD(r2 + lane);
                if (lane < HH-64) irB1 = ALD(r2 + 64 + lane);
            }
        } else {
            do { cin = ALDA(cnt_in); } while (cin < 3u);
            sZ[0][lane]       = ALD(zring + lane);
            sZ[0][64 + lane]  = ALD(zring + 64 + lane);
            sZ[0][128 + lane] = ALD(zring + 128 + lane);
            sZ[0][192 + lane] = ALD(zring + 192 + lane);
            if (lane < G4-256) sZ[0][256 + lane] = ALD(zring + 256 + lane);
            const float* r1 = zring + (size_t)(1 % CZ) * ZSLOT;
            zA0 = ALD(r1 + lane);        zA1 = ALD(r1 + 64 + lane);
            zA2 = ALD(r1 + 128 + lane);  zA3 = ALD(r1 + 192 + lane);
            zA4 = (lane < G4-256) ? ALD(r1 + 256 + lane) : 0.0f;
            const float* r2 = zring + (size_t)(2 % CZ) * ZSLOT;
            zB0 = ALD(r2 + lane);        zB1 = ALD(r2 + 64 + lane);
            zB2 = ALD(r2 + 128 + lane);  zB3 = ALD(r2 + 192 + lane);
            zB4 = (lane < G4-256) ? ALD(r2 + 256 + lane) : 0.0f;
        }
    }
    __syncthreads();

    float c = 0.0f;            // cell state (B stages, tid < 74)

#define ACC4(W, Q) { f4 v_ = vv[Q]; \
            a0 = fmaf(W[0], v_[0], a0); a1 = fmaf(W[1], v_[1], a1); \
            a2 = fmaf(W[2], v_[2], a2); a3 = fmaf(W[3], v_[3], a3); }

#define STEP(T, IR0, IR1, Z0, Z1, Z2, Z3, Z4)                                   \
{                                                                               \
    const int b_ = (T) & 1;                                                     \
    if (isRowT) {                                                               \
        float a0, a1 = 0.f, a2 = 0.f, a3 = 0.f;                                 \
        const f4* vv;                                                           \
        if (isA) { vv = ((const f4*)sIn[b_]) + half*(KH/4); a0 = bias; }        \
        else { vv = ((const f4*)sH) + half*(KH/4);                              \
               a0 = (half == 0 && row < G4) ? sZ[b_][row] : 0.0f; }             \
        ACC4(w0,0) ACC4(w1,1) ACC4(w2,2) ACC4(w3,3) ACC4(w4,4)                  \
        ACC4(w5,5) ACC4(w6,6) ACC4(w7,7) ACC4(w8,8) ACC4(w9,9)                  \
        float p_ = (a0 + a1) + (a2 + a3);                                       \
        p_ += __shfl_xor(p_, 1, 64);                                            \
        if (isA) { if (half == 0 && row < G4) sZ[b_][row] = p_; }               \
        else { float s_ = __builtin_amdgcn_rcpf(1.0f + __expf(-p_));            \
               const bool isG_ = (row >= 2*HH) && (row < 3*HH);                 \
               float g_ = isG_ ? fmaf(2.0f, s_, -1.0f) : s_;                    \
               if (half == 0 && row < G4) sG[row] = g_; }                       \
    } else if (tid < W6) {  /* prefetch wave: depth-2 pipelined loads */        \
        const int lane = tid - W5;                                              \
        const int nb_ = ((T) + 1) & 1;                                          \
        int s_ = (T) + 3; if (s_ > TT-1) s_ = TT-1;                             \
        if (isA) {                                                              \
            sIn[nb_][lane] = IR0;                                               \
            if (lane < HH-64) sIn[nb_][64+lane] = IR1;                          \
            if (l == 0) {                                                       \
                const float* xs_ = seasons + (size_t)s_ * HH;                   \
                IR0 = xs_[lane];                                                \
                if (lane < HH-64) IR1 = xs_[64+lane];                           \
            } else {                                                            \
                unsigned need_ = (unsigned)(s_ + 1); if (need_ > TT) need_ = TT;\
                if (cin < need_) { do { cin = ALDA(cnt_in); } while (cin < need_); } \
                const float* rs_ = hring_in + (size_t)(s_ % CH) * SLOT;         \
                IR0 = ALD(rs_ + lane);                                          \
                if (lane < HH-64) IR1 = ALD(rs_ + 64 + lane);                   \
                cin = ALD(cnt_in);                                              \
            }                                                                   \
        } else {                                                                \
            sZ[nb_][lane] = Z0; sZ[nb_][64+lane] = Z1;                          \
            sZ[nb_][128+lane] = Z2; sZ[nb_][192+lane] = Z3;                     \
            if (lane < G4-256) sZ[nb_][256+lane] = Z4;                          \
            unsigned need_ = (unsigned)(s_ + 1); if (need_ > TT) need_ = TT;    \
            if (cin < need_) { do { cin = ALDA(cnt_in); } while (cin < need_); }\
            const float* rs_ = zring + (size_t)(s_ % CZ) * ZSLOT;               \
            Z0 = ALD(rs_ + lane); Z1 = ALD(rs_ + 64 + lane);                    \
            Z2 = ALD(rs_ + 128 + lane); Z3 = ALD(rs_ + 192 + lane);             \
            if (lane < G4-256) Z4 = ALD(rs_ + 256 + lane);                      \
            cin = ALD(cnt_in);                                                  \
        }                                                                       \
    } else {  /* publish wave: stores + release only */                         \
        const int lane = tid - W6;                                              \
        if ((T) > 0) {                                                          \
            if (isA) {                                                          \
                while ((long)((T)-1) - (long)cons > (long)(CZ - 8))             \
                    cons = ALD(cnt_dn);                                         \
                const int ob_ = ((T)-1) & 1;                                    \
                float v0_ = sZ[ob_][lane],      v1_ = sZ[ob_][64+lane];         \
                float v2_ = sZ[ob_][128+lane],  v3_ = sZ[ob_][192+lane];        \
                float v4_ = (lane < G4-256) ? sZ[ob_][256+lane] : 0.0f;         \
                float* rp_ = zring + (size_t)(((T)-1) % CZ) * ZSLOT;            \
                AST(rp_ + lane, v0_);        AST(rp_ + 64 + lane, v1_);         \
                AST(rp_ + 128 + lane, v2_);  AST(rp_ + 192 + lane, v3_);        \
                if (lane < G4-256) AST(rp_ + 256 + lane, v4_);                  \
                if (lane == 0) ASTR(cnt_out, (unsigned)(T));                    \
            } else if (l < 2) {                                                 \
                while ((long)((T)-1) - (long)cons > (long)(CH - 8))             \
                    cons = ALD(cnt_dn);                                         \
                float h0_ = sH[lane];                                           \
                float h1_ = (lane < HH-64) ? sH[64+lane] : 0.0f;                \
                float* rp_ = hring_out + (size_t)(((T)-1) % CH) * SLOT;         \
                AST(rp_ + lane, h0_);                                           \
                if (lane < HH-64) AST(rp_ + 64 + lane, h1_);                    \
                if (lane == 0) ASTR(cnt_out, (unsigned)(T));                    \
            } else {                                                            \
                if (lane == 0) AST(cnt_out, (unsigned)(T));                     \
                float p_ = wl0 * sH[lane];                                      \
                if (lane < HH-64) p_ += wl1 * sH[64 + lane];                    \
                _Pragma("unroll")                                               \
                for (int m_ = 32; m_ >= 1; m_ >>= 1)                            \
                    p_ += __shfl_xor(p_, m_, 64);                               \
                if (lane == 0) out[(T)-1] = fmaxf(p_ + blin, 0.0f);             \
            }                                                                   \
        }                                                                       \
    }                                                                           \
    BAR();                                                                      \
    if (!isA) {                                                                 \
        if (tid < HH) {                                                         \
            float iv_ = sG[tid], fv_ = sG[HH+tid];                              \
            float gv_ = sG[2*HH+tid], ov_ = sG[3*HH+tid];                       \
            c = fmaf(fv_, c, iv_ * gv_);                                        \
            float e_  = __expf(-2.0f * fabsf(c));                               \
            float th_ = copysignf((1.0f - e_) * __builtin_amdgcn_rcpf(1.0f + e_), c); \
            sH[tid] = ov_ * th_;                                                \
        }                                                                       \
        BAR();                                                                  \
    }                                                                           \
}

    for (int t = 0; t < TT; t += 2) {       // TT even: exact
        STEP(t,     irA0, irA1, zA0, zA1, zA2, zA3, zA4)
        STEP(t + 1, irB0, irB1, zB0, zB1, zB2, zB3, zB4)
    }
#undef STEP
#undef ACC4

    // ---- epilogue: publish slot TT-1 / final output ----
    if (tid >= W6) {
        const int lane = tid - W6;
        if (isA) {
            const int ob = (TT-1) & 1;
            float v0 = sZ[ob][lane],      v1 = sZ[ob][64+lane];
            float v2 = sZ[ob][128+lane],  v3 = sZ[ob][192+lane];
            float v4 = (lane < G4-256) ? sZ[ob][256+lane] : 0.0f;
            float* rp = zring + (size_t)((TT-1) % CZ) * ZSLOT;
            AST(rp + lane, v0);        AST(rp + 64 + lane, v1);
            AST(rp + 128 + lane, v2);  AST(rp + 192 + lane, v3);
            if (lane < G4-256) AST(rp + 256 + lane, v4);
            if (lane == 0) ASTR(cnt_out, (unsigned)TT);
        } else if (l < 2) {
            float h0 = sH[lane];
            float h1 = (lane < HH-64) ? sH[64+lane] : 0.0f;
            float* rp = hring_out + (size_t)((TT-1) % CH) * SLOT;
            AST(rp + lane, h0);
            if (lane < HH-64) AST(rp + 64 + lane, h1);
            if (lane == 0) ASTR(cnt_out, (unsigned)TT);
        } else {
            float p = wl0 * sH[lane];
            if (lane < HH-64) p += wl1 * sH[64 + lane];
            #pragma unroll
            for (int m = 32; m >= 1; m >>= 1)
                p += __shfl_xor(p, m, 64);
            if (lane == 0) out[TT-1] = fmaxf(p + blin, 0.0f);
        }
    }
}

extern "C" void kernel_launch(void* const* d_in, const int* in_sizes, int n_in,
                              void* d_out, int out_size, void* d_ws, size_t ws_size,
                              hipStream_t stream)
{
    (void)in_sizes; (void)n_in; (void)out_size;
    const float* seasons = (const float*)d_in[0];
    const float* W_ih  = (const float*)d_in[1];
    const float* W_hh  = (const float*)d_in[2];
    const float* b_ih  = (const float*)d_in[3];
    const float* b_hh  = (const float*)d_in[4];
    const float* W_lin = (const float*)d_in[5];
    const float* b_lin = (const float*)d_in[6];
    float* out = (float*)d_out;

    unsigned* ctrl = (unsigned*)d_ws;
    float* zbase = (float*)((char*)d_ws + 4096);
    long avail = ((long)ws_size - 4096) / 4;       // floats available
    int CZ = 256, CH = 1024;
    while ((3L*CZ*ZSLOT + 2L*CH*SLOT) > avail && CZ > 16) { CZ >>= 1; CH >>= 1; }
    if (CZ < 16) CZ = 16;
    if (CH < 16) CH = 16;
    float* hbase = zbase + 3L * CZ * ZSLOT;

    hipLaunchKernelGGL(init_ctrl, dim3(1), dim3(256), 0, stream, ctrl);
    hipLaunchKernelGGL(lstm_pipe6, dim3(6), dim3(NT), 0, stream,
                       seasons, W_ih, W_hh, b_ih, b_hh, W_lin, b_lin,
                       out, ctrl, zbase, hbase, CZ, CH);
}